// Round 4
// baseline (156.647 us; speedup 1.0000x reference)
//
#include <hip/hip_runtime.h>
#include <math.h>

// Round 10: fit the allocator instead of fighting it.
// R7/R9 evidence: allocator pins VGPR=80 regardless of launch_bounds; a
// 24-residue-per-thread stash (~160 live floats) therefore spills (WRITE_SIZE
// 83-100MB vs 75.5 ideal, VALUBusy ~19%). This round halves per-thread state:
//  - 4 residues/thread, 2 waves (128 threads) per chain, 4096 blocks.
//  - params 36 + stash 36 (params die as stash fills) -> ~80-90 peak liveness.
//  - phase A serial chain: 12 steps (was 24); waves double to 8192 -> 2x TLP.
//  - cross-wave fixup: wave0 total (12 floats) via LDS + one __syncthreads
//    (R6 mechanism, known container-safe). No sched_barrier anywhere.
//  - replay fused into float4 stores (no out[] array), windows clamped for u=0.

#define LCH 512

struct Xf { float r[9]; float t[3]; };

__device__ __forceinline__ Xf xf_compose(const Xf& A, const Xf& B) {
  Xf C;
#pragma unroll
  for (int i = 0; i < 3; ++i) {
    float a0 = A.r[3*i+0], a1 = A.r[3*i+1], a2 = A.r[3*i+2];
    C.r[3*i+0] = a0*B.r[0] + a1*B.r[3] + a2*B.r[6];
    C.r[3*i+1] = a0*B.r[1] + a1*B.r[4] + a2*B.r[7];
    C.r[3*i+2] = a0*B.r[2] + a1*B.r[5] + a2*B.r[8];
    C.t[i]     = a0*B.t[0] + a1*B.t[1] + a2*B.t[2] + A.t[i];
  }
  return C;
}

// P := P o Delta(theta, len, tau), sparsity-aware (~31 FMA).
__device__ __forceinline__ void xf_step(Xf& P, float theta, float len, float tau) {
  float st, ct, sx, cx;
  __sincosf(theta, &st, &ct);
  __sincosf(tau, &sx, &cx);
  float ux = -ct, uy = cx*st, uz = sx*st;      // delta col0 (= d_local / L)
  float v0 = -st, v1 = -ct*cx, v2 = -ct*sx;    // delta col1; col2 = (0,-sx,cx)
  float c00 = P.r[0]*ux + P.r[1]*uy + P.r[2]*uz;
  float c10 = P.r[3]*ux + P.r[4]*uy + P.r[5]*uz;
  float c20 = P.r[6]*ux + P.r[7]*uy + P.r[8]*uz;
  float c01 = P.r[0]*v0 + P.r[1]*v1 + P.r[2]*v2;
  float c11 = P.r[3]*v0 + P.r[4]*v1 + P.r[5]*v2;
  float c21 = P.r[6]*v0 + P.r[7]*v1 + P.r[8]*v2;
  float c02 = P.r[2]*cx - P.r[1]*sx;
  float c12 = P.r[5]*cx - P.r[4]*sx;
  float c22 = P.r[8]*cx - P.r[7]*sx;
  P.t[0] += len*c00; P.t[1] += len*c10; P.t[2] += len*c20;
  P.r[0]=c00; P.r[1]=c01; P.r[2]=c02;
  P.r[3]=c10; P.r[4]=c11; P.r[5]=c12;
  P.r[6]=c20; P.r[7]=c21; P.r[8]=c22;
}

__device__ __forceinline__ void xf_set_delta(Xf& P, float theta, float len, float tau) {
  float st, ct, sx, cx;
  __sincosf(theta, &st, &ct);
  __sincosf(tau, &sx, &cx);
  float ux = -ct, uy = cx*st, uz = sx*st;
  P.r[0]=ux; P.r[1]=-st;    P.r[2]=0.f;
  P.r[3]=uy; P.r[4]=-ct*cx; P.r[5]=-sx;
  P.r[6]=uz; P.r[7]=-ct*sx; P.r[8]=cx;
  P.t[0]=len*ux; P.t[1]=len*uy; P.t[2]=len*uz;
}

__device__ __forceinline__ void xf_identity(Xf& A) {
  A.r[0]=1.f; A.r[1]=0.f; A.r[2]=0.f;
  A.r[3]=0.f; A.r[4]=1.f; A.r[5]=0.f;
  A.r[6]=0.f; A.r[7]=0.f; A.r[8]=1.f;
  A.t[0]=0.f; A.t[1]=0.f; A.t[2]=0.f;
}

__device__ __forceinline__ Xf xf_shfl_up(const Xf& P, int d) {
  Xf O;
#pragma unroll
  for (int i = 0; i < 9; ++i) O.r[i] = __shfl_up(P.r[i], d, 64);
#pragma unroll
  for (int i = 0; i < 3; ++i) O.t[i] = __shfl_up(P.t[i], d, 64);
  return O;
}

// replay matvec for output float f (0..35) of this thread; f compile-time.
#define REP(f) (A.r[3*((f)%3)+0]*sx[(f)/3] + A.r[3*((f)%3)+1]*sy[(f)/3] \
              + A.r[3*((f)%3)+2]*sz[(f)/3] + A.t[(f)%3])

__global__ __launch_bounds__(128) void nerf_r10_kernel(
    const float* __restrict__ g_phi, const float* __restrict__ g_psi,
    const float* __restrict__ g_omg, const float* __restrict__ g_bl,
    const float* __restrict__ g_ba, float* __restrict__ g_out)
{
  __shared__ float s_tot[12];           // wave-0 inclusive total

  const int t    = threadIdx.x;         // 0..127 (= u, thread index in chain)
  const int lane = t & 63;
  const int wave = t >> 6;
  const int chain = blockIdx.x;

  const float* phir = g_phi + (size_t)chain * LCH;
  const float* psir = g_psi + (size_t)chain * LCH;
  const float* omgr = g_omg + (size_t)chain * LCH;
  const float* blr  = g_bl  + (size_t)chain * (LCH*3);
  const float* bar  = g_ba  + (size_t)chain * (LCH*3);

  const int j4  = 4 * t;     // window is residues [4t-1 .. 4t+2]
  const int b12 = 12 * t;

  // ---- vectorized window loads (t=0 pre-roll clamped; junk discarded) ----
  float PS[4], OM[4], PH[4], BL[12], BA[12];
  {
    float  e0 = psir[j4 ? j4 - 1 : 0];
    float4 v  = *(const float4*)(psir + j4);    // 4t..4t+3 (last unused)
    PS[0]=e0; PS[1]=v.x; PS[2]=v.y; PS[3]=v.z;
  }
  {
    float  e0 = omgr[j4 ? j4 - 1 : 0];
    float4 v  = *(const float4*)(omgr + j4);
    OM[0]=e0; OM[1]=v.x; OM[2]=v.y; OM[3]=v.z;
  }
  {
    float4 v = *(const float4*)(phir + j4);     // phi[4t .. 4t+3] = phi[r+1] set
    PH[0]=v.x; PH[1]=v.y; PH[2]=v.z; PH[3]=v.w;
  }
  {
    float  e0  = blr[b12 >= 3 ? b12 - 3 : 0];
    float2 e12 = *(const float2*)(blr + (b12 >= 2 ? b12 - 2 : 0));
    float4 w0  = *(const float4*)(blr + b12);
    float4 w1  = *(const float4*)(blr + b12 + 4);
    float  e8  = blr[b12 + 8];
    BL[0]=e0;   BL[1]=e12.x; BL[2]=e12.y;
    BL[3]=w0.x; BL[4]=w0.y;  BL[5]=w0.z;  BL[6]=w0.w;
    BL[7]=w1.x; BL[8]=w1.y;  BL[9]=w1.z;  BL[10]=w1.w;
    BL[11]=e8;
  }
  {
    float  e0  = bar[b12 >= 3 ? b12 - 3 : 0];
    float2 e12 = *(const float2*)(bar + (b12 >= 2 ? b12 - 2 : 0));
    float4 w0  = *(const float4*)(bar + b12);
    float4 w1  = *(const float4*)(bar + b12 + 4);
    float  e8  = bar[b12 + 8];
    BA[0]=e0;   BA[1]=e12.x; BA[2]=e12.y;
    BA[3]=w0.x; BA[4]=w0.y;  BA[5]=w0.z;  BA[6]=w0.w;
    BA[7]=w1.x; BA[8]=w1.y;  BA[9]=w1.z;  BA[10]=w1.w;
    BA[11]=e8;
  }

  // ---- Phase A: 12 serial steps, stash partial translations ----
  // step a of window residue m: a=0 (N): theta=ba1 L=bl2 tau=psi
  //   a=1 (CA): theta=ba2 L=bl0 tau=omega;  a=2 (C): theta=ba0 L=bl1 tau=phi[r+1]
  Xf P;
  float sx[12], sy[12], sz[12];
#pragma unroll
  for (int k = 0; k < 12; ++k) {
    const int m = k / 3, a = k - 3*m;   // compile-time after unroll
    float th, ln, ta;
    if (a == 0)      { th = BA[3*m+1]; ln = BL[3*m+2]; ta = PS[m]; }
    else if (a == 1) { th = BA[3*m+2]; ln = BL[3*m+0]; ta = OM[m]; }
    else             { th = BA[3*m+0]; ln = BL[3*m+1]; ta = PH[m]; }
    if (k == 0) xf_set_delta(P, th, ln, ta);
    else        xf_step(P, th, ln, ta);
    sx[k] = P.t[0]; sy[k] = P.t[1]; sz[k] = P.t[2];
    if (k == 2 && t == 0) xf_identity(P);  // discard t=0 pre-roll
  }

  // ---- intra-wave inclusive scan (non-commutative) ----
#pragma unroll
  for (int d = 1; d < 64; d <<= 1) {
    Xf O = xf_shfl_up(P, d);
    if (lane >= d) P = xf_compose(O, P);
  }

  // wave-0 total -> LDS for wave 1
  if (wave == 0 && lane == 63) {
#pragma unroll
    for (int i = 0; i < 9; ++i) s_tot[i] = P.r[i];
#pragma unroll
    for (int i = 0; i < 3; ++i) s_tot[9+i] = P.t[i];
  }
  Xf E = xf_shfl_up(P, 1);   // within-wave exclusive (junk for lane 0)
  __syncthreads();

  // ---- prefix transform A = I0 [o W0total] [o E] ----
  Xf A;
  {
    const float ax=17.047f, ay=14.099f, az=3.625f;
    const float bx_=16.967f, by_=12.784f, bz_=4.338f;
    const float cx_=15.685f, cy_=12.755f, cz_=5.133f;
    float abx=bx_-ax, aby=by_-ay, abz=bz_-az;
    float vx=cx_-bx_, vy=cy_-by_, vz=cz_-bz_;
    float vn = sqrtf(vx*vx+vy*vy+vz*vz) + 1e-8f;
    vx/=vn; vy/=vn; vz/=vn;
    float crx = aby*vz - abz*vy;
    float cry = abz*vx - abx*vz;
    float crz = abx*vy - aby*vx;
    float cn = sqrtf(crx*crx+cry*cry+crz*crz) + 1e-8f;
    float nx=crx/cn, ny=cry/cn, nz=crz/cn;
    float mx = ny*vz - nz*vy;
    float my = nz*vx - nx*vz;
    float mz = nx*vy - ny*vx;
    A.r[0]=vx; A.r[1]=mx; A.r[2]=nx;
    A.r[3]=vy; A.r[4]=my; A.r[5]=ny;
    A.r[6]=vz; A.r[7]=mz; A.r[8]=nz;
    A.t[0]=cx_; A.t[1]=cy_; A.t[2]=cz_;
  }
  if (wave == 1) {
    Xf T;
#pragma unroll
    for (int i = 0; i < 9; ++i) T.r[i] = s_tot[i];
#pragma unroll
    for (int i = 0; i < 3; ++i) T.t[i] = s_tot[9+i];
    A = xf_compose(A, T);
  }
  if (lane > 0) A = xf_compose(A, E);

  // ---- fused replay + direct aligned dwordx4 stores ----
  // thread t owns output floats [36t, 36t+36) of the chain row.
  float* orow = g_out + (size_t)chain * 4608 + 36 * t;
#pragma unroll
  for (int q = 0; q < 9; ++q) {
    float4 v;
    v.x = REP(4*q + 0);
    v.y = REP(4*q + 1);
    v.z = REP(4*q + 2);
    v.w = REP(4*q + 3);
    *(float4*)(orow + 4*q) = v;
  }
  if (t == 0) {   // init block replaces the 3 junk pre-roll atoms
    float4 i0; i0.x=17.047f; i0.y=14.099f; i0.z=3.625f;  i0.w=16.967f;
    float4 i1; i1.x=12.784f; i1.y=4.338f;  i1.z=15.685f; i1.w=12.755f;
    *(float4*)(orow + 0) = i0;
    *(float4*)(orow + 4) = i1;
    orow[8] = 5.133f;
  }
}

extern "C" void kernel_launch(void* const* d_in, const int* in_sizes, int n_in,
                              void* d_out, int out_size, void* d_ws, size_t ws_size,
                              hipStream_t stream) {
  const float* phi = (const float*)d_in[0];
  const float* psi = (const float*)d_in[1];
  const float* omg = (const float*)d_in[2];
  const float* bl  = (const float*)d_in[3];
  const float* ba  = (const float*)d_in[4];
  float* out = (float*)d_out;
  const int B = in_sizes[0] / LCH;          // 4096 chains
  hipLaunchKernelGGL(nerf_r10_kernel, dim3(B), dim3(128), 0, stream,
                     phi, psi, omg, bl, ba, out);
}